// Round 3
// baseline (651.778 us; speedup 1.0000x reference)
//
#include <hip/hip_runtime.h>
#include <math.h>

#define N_IMG 8
#define N_ANCH 250000
#define PRE_K 2000
#define POST_K 1000
#define SORT_N 2048
#define EQ_CAP 4096
#define NMS_WORDS 32   // ceil(2000/64)
#define NCHUNK 32      // ceil(2000/64) row-chunks of 64

#define IMG_W_M1 1332.0f
#define IMG_H_M1 799.0f
#define DCLIP 4.135166556742356f
#define NMS_T 0.7f

__device__ __forceinline__ float rn_add(float a, float b){ return __fadd_rn(a,b); }
__device__ __forceinline__ float rn_sub(float a, float b){ return __fsub_rn(a,b); }
__device__ __forceinline__ float rn_mul(float a, float b){ return __fmul_rn(a,b); }
__device__ __forceinline__ float rn_div(float a, float b){ return __fdiv_rn(a,b); }

// monotonic float->uint mapping (order-preserving, larger float -> larger uint)
__device__ __forceinline__ unsigned int mono_of(float f){
  unsigned int u = __float_as_uint(f);
  return u ^ ((u >> 31) ? 0xFFFFFFFFu : 0x80000000u);
}

__device__ __forceinline__ unsigned long long shfl_u64(unsigned long long v, int lane){
  int lo = __shfl((int)(unsigned int)(v & 0xFFFFFFFFull), lane, 64);
  int hi = __shfl((int)(unsigned int)(v >> 32), lane, 64);
  return ((unsigned long long)(unsigned int)hi << 32) | (unsigned long long)(unsigned int)lo;
}

// exact-op-order IoU > 0.7 test (mirrors reference float32 op sequence)
__device__ __forceinline__ bool iou_gt(float x1,float y1,float x2,float y2,float a1,
                                       float X1,float Y1,float X2,float Y2,float a2){
  float ltx = fmaxf(x1, X1), lty = fmaxf(y1, Y1);
  float rbx = fminf(x2, X2), rby = fminf(y2, Y2);
  float wx = fmaxf(rn_add(rn_sub(rbx, ltx), 1.0f), 0.0f);
  float wy = fmaxf(rn_add(rn_sub(rby, lty), 1.0f), 0.0f);
  float inter = rn_mul(wx, wy);
  float iou = rn_div(inter, rn_sub(rn_add(a1, a2), inter));
  return iou > NMS_T;
}

// ---------------- kernel 0: init ws state ----------------
__global__ void k_init(unsigned int* hist, unsigned int* state, unsigned int* cnt){
  int t = blockIdx.x * blockDim.x + threadIdx.x;
  int tot = N_IMG * 2048;
  for (int i = t; i < tot; i += gridDim.x * blockDim.x) hist[i] = 0;
  if (t < N_IMG){
    state[2*t] = 0;          // prefix
    state[2*t+1] = PRE_K;    // remaining
    cnt[2*t] = 0;            // cnt_gt
    cnt[2*t+1] = 0;          // cnt_eq
  }
}

// ---------------- radix-select histogram pass ----------------
__global__ void k_hist(const float* __restrict__ obj, unsigned int* __restrict__ hist,
                       const unsigned int* __restrict__ state, int shift, int hishift){
  __shared__ unsigned int lh[2048];
  int img = blockIdx.y;
  for (int i = threadIdx.x; i < 2048; i += blockDim.x) lh[i] = 0;
  __syncthreads();
  unsigned int prefix = state[2*img];
  unsigned int phi = (hishift >= 32) ? 0u : (prefix >> hishift);
  const float* o = obj + (size_t)img * N_ANCH;
  int stride = gridDim.x * blockDim.x;
  for (int i = blockIdx.x * blockDim.x + threadIdx.x; i < N_ANCH; i += stride){
    unsigned int key = mono_of(o[i]);
    bool ok = (hishift >= 32) || ((key >> hishift) == phi);
    if (ok) atomicAdd(&lh[(key >> shift) & 2047], 1u);
  }
  __syncthreads();
  for (int i = threadIdx.x; i < 2048; i += blockDim.x)
    if (lh[i]) atomicAdd(&hist[img*2048 + i], lh[i]);
}

// ---------------- radix-select scan pass (also zeros hist for next pass) ----------------
__global__ void k_scan(unsigned int* hist, unsigned int* state, int shift){
  int img = blockIdx.x;
  unsigned int* h = hist + img * 2048;
  if (threadIdx.x == 0){
    unsigned int remaining = state[2*img+1];
    unsigned int prefix = state[2*img];
    unsigned int cum = 0;
    for (int d = 2047; d >= 0; --d){
      unsigned int c = h[d];
      if (cum + c >= remaining){
        prefix |= ((unsigned int)d) << shift;
        remaining -= cum;
        break;
      }
      cum += c;
    }
    state[2*img] = prefix;
    state[2*img+1] = remaining;
  }
  __syncthreads();
  for (int i = threadIdx.x; i < 2048; i += blockDim.x) h[i] = 0;
}

// ---------------- collect: keys > T into sel, keys == T into eqbuf ----------------
__global__ void k_collect(const float* __restrict__ obj, const unsigned int* __restrict__ state,
                          unsigned int* cnt, unsigned long long* sel, unsigned int* eqbuf){
  int img = blockIdx.y;
  unsigned int T = state[2*img];
  const float* o = obj + (size_t)img * N_ANCH;
  int stride = gridDim.x * blockDim.x;
  for (int i = blockIdx.x * blockDim.x + threadIdx.x; i < N_ANCH; i += stride){
    unsigned int key = mono_of(o[i]);
    if (key > T){
      unsigned int slot = atomicAdd(&cnt[2*img], 1u);
      if (slot < PRE_K)
        sel[(size_t)img*SORT_N + slot] =
          ((unsigned long long)key << 32) | (unsigned long long)(~(unsigned int)i);
    } else if (key == T){
      unsigned int e = atomicAdd(&cnt[2*img+1], 1u);
      if (e < EQ_CAP) eqbuf[img*EQ_CAP + e] = (unsigned int)i;
    }
  }
}

// ---------------- finalize: pick R smallest-index ties, pad sort buffer ----------------
__global__ void k_finalize(const unsigned int* state, const unsigned int* cnt,
                           unsigned long long* sel, const unsigned int* eqbuf){
  int img = blockIdx.x;
  unsigned int R = state[2*img+1];
  unsigned int G = PRE_K - R;
  unsigned int T = state[2*img];
  unsigned int E = cnt[2*img+1]; if (E > EQ_CAP) E = EQ_CAP;
  if (threadIdx.x == 0){
    unsigned int last = 0; bool first = true;
    for (unsigned int r = 0; r < R; ++r){
      unsigned int best = 0xFFFFFFFFu;
      for (unsigned int e = 0; e < E; ++e){
        unsigned int v = eqbuf[img*EQ_CAP + e];
        if ((first || v > last) && v < best) best = v;
      }
      sel[(size_t)img*SORT_N + G + r] =
        ((unsigned long long)T << 32) | (unsigned long long)(~best);
      last = best; first = false;
    }
  }
  for (int i = PRE_K + threadIdx.x; i < SORT_N; i += blockDim.x)
    sel[(size_t)img*SORT_N + i] = 0ull;
}

// ---------------- bitonic sort 2048 u64 descending (score desc, idx asc) ----------------
__global__ void __launch_bounds__(1024) k_sort(unsigned long long* sel){
  __shared__ unsigned long long a[SORT_N];
  int img = blockIdx.x;
  for (int i = threadIdx.x; i < SORT_N; i += blockDim.x) a[i] = sel[(size_t)img*SORT_N + i];
  __syncthreads();
  for (int k = 2; k <= SORT_N; k <<= 1){
    for (int j = k >> 1; j > 0; j >>= 1){
      for (int i = threadIdx.x; i < SORT_N; i += blockDim.x){
        int ixj = i ^ j;
        if (ixj > i){
          bool up = ((i & k) == 0);
          unsigned long long x = a[i], y = a[ixj];
          if ((x < y) == up){ a[i] = y; a[ixj] = x; }  // descending sort
        }
      }
      __syncthreads();
    }
  }
  for (int i = threadIdx.x; i < SORT_N; i += blockDim.x) sel[(size_t)img*SORT_N + i] = a[i];
}

// ---------------- decode + clip + area/valid for the selected 2000 ----------------
__global__ void k_decode(const float* __restrict__ anchors, const float* __restrict__ obj,
                         const float* __restrict__ deltas, const unsigned long long* __restrict__ sel,
                         float* __restrict__ boxes, float* __restrict__ scores,
                         float* __restrict__ areas, unsigned int* __restrict__ valid){
  int img = blockIdx.y;
  int k = blockIdx.x * blockDim.x + threadIdx.x;
  if (k >= PRE_K) return;
  unsigned long long pk = sel[(size_t)img*SORT_N + k];
  unsigned int idx = ~(unsigned int)(pk & 0xFFFFFFFFull);
  float4 a = ((const float4*)anchors)[idx];
  float4 d = ((const float4*)deltas)[(size_t)img*N_ANCH + idx];
  float sc = obj[(size_t)img*N_ANCH + idx];

  float w  = rn_add(rn_sub(a.z, a.x), 1.0f);
  float h  = rn_add(rn_sub(a.w, a.y), 1.0f);
  float cx = rn_add(a.x, rn_mul(0.5f, w));
  float cy = rn_add(a.y, rn_mul(0.5f, h));
  float dw = fminf(d.z, DCLIP);
  float dh = fminf(d.w, DCLIP);
  float pcx = rn_add(rn_mul(d.x, w), cx);
  float pcy = rn_add(rn_mul(d.y, h), cy);
  float pw = rn_mul((float)exp((double)dw), w);   // correctly-rounded f32 exp
  float ph = rn_mul((float)exp((double)dh), h);
  float x1 = rn_sub(pcx, rn_mul(0.5f, pw));
  float y1 = rn_sub(pcy, rn_mul(0.5f, ph));
  float x2 = rn_sub(rn_add(pcx, rn_mul(0.5f, pw)), 1.0f);
  float y2 = rn_sub(rn_add(pcy, rn_mul(0.5f, ph)), 1.0f);
  x1 = fminf(fmaxf(x1, 0.0f), IMG_W_M1);
  x2 = fminf(fmaxf(x2, 0.0f), IMG_W_M1);
  y1 = fminf(fmaxf(y1, 0.0f), IMG_H_M1);
  y2 = fminf(fmaxf(y2, 0.0f), IMG_H_M1);
  float bw = rn_add(rn_sub(x2, x1), 1.0f);
  float bh = rn_add(rn_sub(y2, y1), 1.0f);
  ((float4*)boxes)[(size_t)img*PRE_K + k] = make_float4(x1, y1, x2, y2);
  scores[img*PRE_K + k] = sc;
  areas[img*PRE_K + k]  = rn_mul(bw, bh);
  valid[img*PRE_K + k]  = (bw >= 0.0f && bh >= 0.0f) ? 1u : 0u;
}

// ---------------- NMS suppression bitmask (upper triangle) ----------------
__global__ void k_mask(const float* __restrict__ boxes, const float* __restrict__ areas,
                       unsigned long long* __restrict__ mask){
  int jblk = blockIdx.x, iblk = blockIdx.y, img = blockIdx.z;
  if (jblk < iblk) return;
  __shared__ float4 jb[64];
  __shared__ float  ja[64];
  int tj = jblk*64 + threadIdx.x;
  if (tj < PRE_K){
    jb[threadIdx.x] = ((const float4*)boxes)[(size_t)img*PRE_K + tj];
    ja[threadIdx.x] = areas[img*PRE_K + tj];
  }
  __syncthreads();
  int i = iblk*64 + threadIdx.x;
  if (i >= PRE_K) return;
  float4 bi = ((const float4*)boxes)[(size_t)img*PRE_K + i];
  float ai = areas[img*PRE_K + i];
  unsigned long long bits = 0;
  int jmax = min(64, PRE_K - jblk*64);
  for (int b = 0; b < jmax; ++b){
    int j = jblk*64 + b;
    if (j <= i) continue;
    float4 bj = jb[b];
    if (iou_gt(bi.x,bi.y,bi.z,bi.w,ai, bj.x,bj.y,bj.z,bj.w,ja[b])) bits |= 1ull << b;
  }
  mask[((size_t)img*PRE_K + i)*NMS_WORDS + jblk] = bits;
}

// ---------------- pipelined greedy reduce + output pack ----------------
// Waves 1-8 stream 64-row mask chunks into a double-buffered LDS ring;
// wave 0 runs the serial reduce with the per-row diagonal word broadcast-read
// from LDS (off the dependent chain).
// __launch_bounds__(1024, 4): 16 waves/CU -> 128-VGPR budget so the 8-row
// register batch (rowv[8]+diag[8] = 32 VGPRs) does NOT spill to scratch
// (round-2 profile showed 64-VGPR cap + 336 KB scratch writes on the
// serial critical path).
__global__ void __launch_bounds__(1024, 4) k_nms_out(const unsigned long long* __restrict__ mask,
                          const unsigned int* __restrict__ valid,
                          const float* __restrict__ boxes, const float* __restrict__ scores,
                          float* __restrict__ out){
  __shared__ unsigned long long lbuf[2][64 * NMS_WORDS];  // 2 x 16 KB
  __shared__ unsigned long long keepw[NMS_WORDS];
  __shared__ unsigned int kpre[NMS_WORDS + 1];
  int img = blockIdx.x;
  int tid = threadIdx.x;
  const unsigned long long* mrow = mask + (size_t)img * PRE_K * NMS_WORDS;
  const int TOT_U64 = PRE_K * NMS_WORDS;  // 64000

  // consumer init: remv word per lane (<32): invalid/out-of-range bits pre-set
  unsigned long long remv = 0;
  if (tid < NMS_WORDS){
    for (int b = 0; b < 64; ++b){
      int i = tid*64 + b;
      bool ok = (i < PRE_K) && (valid[img*PRE_K + i] != 0u);
      if (!ok) remv |= 1ull << b;
    }
  }

  // prologue: load chunk 0 into lbuf[0]
  int lt = tid - 64;  // loader threads 64..575
  if (lt >= 0 && lt < 512){
    int e0 = lt * 4;
    ulonglong2 v0, v1; v0.x = v0.y = v1.x = v1.y = 0ull;
    if (e0 < TOT_U64){
      const ulonglong2* g = (const ulonglong2*)(mrow + e0);
      v0 = g[0]; v1 = g[1];
    }
    ulonglong2* l = (ulonglong2*)&lbuf[0][e0];
    l[0] = v0; l[1] = v1;
  }
  __syncthreads();

  for (int c = 0; c < NCHUNK; ++c){
    // loaders: fetch chunk c+1 into the other buffer
    if (lt >= 0 && lt < 512 && (c + 1) < NCHUNK){
      int e0 = lt * 4;
      int off = (c + 1) * (64 * NMS_WORDS) + e0;
      ulonglong2 v0, v1; v0.x = v0.y = v1.x = v1.y = 0ull;
      if (off < TOT_U64){
        const ulonglong2* g = (const ulonglong2*)(mrow + off);
        v0 = g[0]; v1 = g[1];
      }
      ulonglong2* l = (ulonglong2*)&lbuf[(c + 1) & 1][e0];
      l[0] = v0; l[1] = v1;
    }
    // consumer: serial reduce over the 64 rows of chunk c (8-row reg batches)
    if (tid < 64){
      int w = tid;
      const unsigned long long* B = &lbuf[c & 1][0];
      unsigned long long Wc = shfl_u64(remv, c);       // remv word c, broadcast
      bool use = (w < NMS_WORDS) && (w >= c);          // sub-diag words are garbage
      for (int s = 0; s < 64; s += 8){
        unsigned long long rowv[8], diag[8];
        #pragma unroll
        for (int t = 0; t < 8; ++t){
          int i = s + t;
          diag[t] = B[i * NMS_WORDS + c];              // same-addr broadcast read
          rowv[t] = use ? B[i * NMS_WORDS + w] : 0ull;
        }
        #pragma unroll
        for (int t = 0; t < 8; ++t){
          unsigned long long m = ((Wc >> (s + t)) & 1ull) ? 0ull : ~0ull;
          Wc   |= diag[t] & m;                          // update keep word (all lanes)
          remv |= rowv[t] & m;                          // update own word
        }
      }
    }
    __syncthreads();
  }

  if (tid < NMS_WORDS) keepw[tid] = ~remv;
  __syncthreads();
  if (tid == 0){
    unsigned int s = 0;
    for (int w = 0; w < NMS_WORDS; ++w){ kpre[w] = s; s += __popcll(keepw[w]); }
    kpre[NMS_WORDS] = s;
  }
  __syncthreads();
  unsigned int nkept = kpre[NMS_WORDS];
  for (int i = tid; i < PRE_K; i += blockDim.x){
    int w = i >> 6, b = i & 63;
    unsigned long long kw = keepw[w];
    bool kept = (kw >> b) & 1ull;
    unsigned long long below = (b == 0) ? 0ull : (kw & ((~0ull) >> (64 - b)));
    unsigned int rank = kpre[w] + (unsigned int)__popcll(below);
    unsigned int pos = kept ? rank : (nkept + (unsigned int)i - rank);
    if (pos < POST_K){
      float4 bx = ((const float4*)boxes)[(size_t)img*PRE_K + i];
      float sc = kept ? scores[img*PRE_K + i] : -1e9f;
      float* o = out + ((size_t)img*POST_K + pos) * 5;
      o[0] = bx.x; o[1] = bx.y; o[2] = bx.z; o[3] = bx.w; o[4] = sc;
    }
  }
}

// ---------------- fallback: in-LDS sequential NMS (small ws) ----------------
__global__ void __launch_bounds__(1024) k_nms_seq(const unsigned int* __restrict__ valid,
                         const float* __restrict__ boxes, const float* __restrict__ areas,
                         const float* __restrict__ scores, float* __restrict__ out){
  __shared__ float4 bxs[PRE_K];
  __shared__ float  ars[PRE_K];
  __shared__ unsigned char kp[PRE_K];
  __shared__ unsigned long long keepw[NMS_WORDS];
  __shared__ unsigned int kpre[NMS_WORDS + 1];
  int img = blockIdx.x, tid = threadIdx.x;
  for (int i = tid; i < PRE_K; i += blockDim.x){
    bxs[i] = ((const float4*)boxes)[(size_t)img*PRE_K + i];
    ars[i] = areas[img*PRE_K + i];
    kp[i]  = (unsigned char)(valid[img*PRE_K + i] != 0u);
  }
  __syncthreads();
  for (int i = 0; i < PRE_K; ++i){
    if (kp[i]){
      float4 bi = bxs[i]; float ai = ars[i];
      for (int j = i + 1 + tid; j < PRE_K; j += blockDim.x){
        if (!kp[j]) continue;
        float4 bj = bxs[j];
        if (iou_gt(bi.x,bi.y,bi.z,bi.w,ai, bj.x,bj.y,bj.z,bj.w,ars[j])) kp[j] = 0;
      }
    }
    __syncthreads();
  }
  if (tid < NMS_WORDS){
    unsigned long long w = 0;
    for (int b = 0; b < 64; ++b){
      int i = tid*64 + b;
      if (i < PRE_K && kp[i]) w |= 1ull << b;
    }
    keepw[tid] = w;
  }
  __syncthreads();
  if (tid == 0){
    unsigned int s = 0;
    for (int w = 0; w < NMS_WORDS; ++w){ kpre[w] = s; s += __popcll(keepw[w]); }
    kpre[NMS_WORDS] = s;
  }
  __syncthreads();
  unsigned int nkept = kpre[NMS_WORDS];
  for (int i = tid; i < PRE_K; i += blockDim.x){
    int w = i >> 6, b = i & 63;
    unsigned long long kw = keepw[w];
    bool kept = (kw >> b) & 1ull;
    unsigned long long below = (b == 0) ? 0ull : (kw & ((~0ull) >> (64 - b)));
    unsigned int rank = kpre[w] + (unsigned int)__popcll(below);
    unsigned int pos = kept ? rank : (nkept + (unsigned int)i - rank);
    if (pos < POST_K){
      float4 bx = bxs[i];
      float sc = kept ? scores[img*PRE_K + i] : -1e9f;
      float* o = out + ((size_t)img*POST_K + pos) * 5;
      o[0] = bx.x; o[1] = bx.y; o[2] = bx.z; o[3] = bx.w; o[4] = sc;
    }
  }
}

extern "C" void kernel_launch(void* const* d_in, const int* in_sizes, int n_in,
                              void* d_out, int out_size, void* d_ws, size_t ws_size,
                              hipStream_t stream) {
  const float* anchors    = (const float*)d_in[0];
  const float* objectness = (const float*)d_in[1];
  const float* deltas     = (const float*)d_in[2];
  float* out = (float*)d_out;
  char* ws = (char*)d_ws;

  unsigned int* hist          = (unsigned int*)(ws + 0);        // 65536
  unsigned int* state         = (unsigned int*)(ws + 65536);    // 64
  unsigned int* cnt           = (unsigned int*)(ws + 65600);    // 64
  unsigned long long* sel     = (unsigned long long*)(ws + 65664);   // 131072
  unsigned int* eqbuf         = (unsigned int*)(ws + 196736);   // 131072
  float* boxes                = (float*)(ws + 327808);          // 256000 (16B aligned)
  float* scores               = (float*)(ws + 583808);          // 64000
  float* areas                = (float*)(ws + 647808);          // 64000
  unsigned int* valid         = (unsigned int*)(ws + 711808);   // 64000
  unsigned long long* mask    = (unsigned long long*)(ws + 775936); // 4096000
  size_t need_mask = 775936 + (size_t)N_IMG * PRE_K * NMS_WORDS * 8;

  hipLaunchKernelGGL(k_init, dim3(32), dim3(256), 0, stream, hist, state, cnt);

  const int shifts[3]   = {21, 10, 0};
  const int hishifts[3] = {32, 21, 10};
  for (int p = 0; p < 3; ++p){
    hipLaunchKernelGGL(k_hist, dim3(128, N_IMG), dim3(256), 0, stream,
                       objectness, hist, state, shifts[p], hishifts[p]);
    hipLaunchKernelGGL(k_scan, dim3(N_IMG), dim3(256), 0, stream, hist, state, shifts[p]);
  }
  hipLaunchKernelGGL(k_collect, dim3(128, N_IMG), dim3(256), 0, stream,
                     objectness, state, cnt, sel, eqbuf);
  hipLaunchKernelGGL(k_finalize, dim3(N_IMG), dim3(256), 0, stream, state, cnt, sel, eqbuf);
  hipLaunchKernelGGL(k_sort, dim3(N_IMG), dim3(1024), 0, stream, sel);
  hipLaunchKernelGGL(k_decode, dim3((PRE_K + 255)/256, N_IMG), dim3(256), 0, stream,
                     anchors, objectness, deltas, sel, boxes, scores, areas, valid);

  if (ws_size >= need_mask){
    hipLaunchKernelGGL(k_mask, dim3(NMS_WORDS, NMS_WORDS, N_IMG), dim3(64), 0, stream,
                       boxes, areas, mask);
    hipLaunchKernelGGL(k_nms_out, dim3(N_IMG), dim3(1024), 0, stream,
                       mask, valid, boxes, scores, out);
  } else {
    hipLaunchKernelGGL(k_nms_seq, dim3(N_IMG), dim3(1024), 0, stream,
                       valid, boxes, areas, scores, out);
  }
}

// Round 4
// 427.603 us; speedup vs baseline: 1.5243x; 1.5243x over previous
//
#include <hip/hip_runtime.h>
#include <math.h>

#define N_IMG 8
#define N_ANCH 250000
#define PRE_K 2000
#define POST_K 1000
#define SORT_N 2048
#define EQ_CAP 4096
#define NMS_WORDS 32   // ceil(2000/64)
#define NCHUNK 32      // ceil(2000/64) row-chunks of 64

#define IMG_W_M1 1332.0f
#define IMG_H_M1 799.0f
#define DCLIP 4.135166556742356f
#define NMS_T 0.7f

__device__ __forceinline__ float rn_add(float a, float b){ return __fadd_rn(a,b); }
__device__ __forceinline__ float rn_sub(float a, float b){ return __fsub_rn(a,b); }
__device__ __forceinline__ float rn_mul(float a, float b){ return __fmul_rn(a,b); }
__device__ __forceinline__ float rn_div(float a, float b){ return __fdiv_rn(a,b); }

// monotonic float->uint mapping (order-preserving, larger float -> larger uint)
__device__ __forceinline__ unsigned int mono_of(float f){
  unsigned int u = __float_as_uint(f);
  return u ^ ((u >> 31) ? 0xFFFFFFFFu : 0x80000000u);
}

__device__ __forceinline__ unsigned long long shfl_u64(unsigned long long v, int lane){
  int lo = __shfl((int)(unsigned int)(v & 0xFFFFFFFFull), lane, 64);
  int hi = __shfl((int)(unsigned int)(v >> 32), lane, 64);
  return ((unsigned long long)(unsigned int)hi << 32) | (unsigned long long)(unsigned int)lo;
}

// exact-op-order IoU > 0.7 test (mirrors reference float32 op sequence)
__device__ __forceinline__ bool iou_gt(float x1,float y1,float x2,float y2,float a1,
                                       float X1,float Y1,float X2,float Y2,float a2){
  float ltx = fmaxf(x1, X1), lty = fmaxf(y1, Y1);
  float rbx = fminf(x2, X2), rby = fminf(y2, Y2);
  float wx = fmaxf(rn_add(rn_sub(rbx, ltx), 1.0f), 0.0f);
  float wy = fmaxf(rn_add(rn_sub(rby, lty), 1.0f), 0.0f);
  float inter = rn_mul(wx, wy);
  float iou = rn_div(inter, rn_sub(rn_add(a1, a2), inter));
  return iou > NMS_T;
}

// ---------------- kernel 0: init ws state ----------------
__global__ void k_init(unsigned int* hist, unsigned int* state, unsigned int* cnt){
  int t = blockIdx.x * blockDim.x + threadIdx.x;
  int tot = N_IMG * 2048;
  for (int i = t; i < tot; i += gridDim.x * blockDim.x) hist[i] = 0;
  if (t < N_IMG){
    state[2*t] = 0;          // prefix
    state[2*t+1] = PRE_K;    // remaining
    cnt[2*t] = 0;            // cnt_gt
    cnt[2*t+1] = 0;          // cnt_eq
  }
}

// ---------------- radix-select histogram pass ----------------
__global__ void k_hist(const float* __restrict__ obj, unsigned int* __restrict__ hist,
                       const unsigned int* __restrict__ state, int shift, int hishift){
  __shared__ unsigned int lh[2048];
  int img = blockIdx.y;
  for (int i = threadIdx.x; i < 2048; i += blockDim.x) lh[i] = 0;
  __syncthreads();
  unsigned int prefix = state[2*img];
  unsigned int phi = (hishift >= 32) ? 0u : (prefix >> hishift);
  const float* o = obj + (size_t)img * N_ANCH;
  int stride = gridDim.x * blockDim.x;
  for (int i = blockIdx.x * blockDim.x + threadIdx.x; i < N_ANCH; i += stride){
    unsigned int key = mono_of(o[i]);
    bool ok = (hishift >= 32) || ((key >> hishift) == phi);
    if (ok) atomicAdd(&lh[(key >> shift) & 2047], 1u);
  }
  __syncthreads();
  for (int i = threadIdx.x; i < 2048; i += blockDim.x)
    if (lh[i]) atomicAdd(&hist[img*2048 + i], lh[i]);
}

// ---------------- radix-select scan pass (also zeros hist for next pass) ----------------
__global__ void k_scan(unsigned int* hist, unsigned int* state, int shift){
  int img = blockIdx.x;
  unsigned int* h = hist + img * 2048;
  if (threadIdx.x == 0){
    unsigned int remaining = state[2*img+1];
    unsigned int prefix = state[2*img];
    unsigned int cum = 0;
    for (int d = 2047; d >= 0; --d){
      unsigned int c = h[d];
      if (cum + c >= remaining){
        prefix |= ((unsigned int)d) << shift;
        remaining -= cum;
        break;
      }
      cum += c;
    }
    state[2*img] = prefix;
    state[2*img+1] = remaining;
  }
  __syncthreads();
  for (int i = threadIdx.x; i < 2048; i += blockDim.x) h[i] = 0;
}

// ---------------- collect: keys > T into sel, keys == T into eqbuf ----------------
__global__ void k_collect(const float* __restrict__ obj, const unsigned int* __restrict__ state,
                          unsigned int* cnt, unsigned long long* sel, unsigned int* eqbuf){
  int img = blockIdx.y;
  unsigned int T = state[2*img];
  const float* o = obj + (size_t)img * N_ANCH;
  int stride = gridDim.x * blockDim.x;
  for (int i = blockIdx.x * blockDim.x + threadIdx.x; i < N_ANCH; i += stride){
    unsigned int key = mono_of(o[i]);
    if (key > T){
      unsigned int slot = atomicAdd(&cnt[2*img], 1u);
      if (slot < PRE_K)
        sel[(size_t)img*SORT_N + slot] =
          ((unsigned long long)key << 32) | (unsigned long long)(~(unsigned int)i);
    } else if (key == T){
      unsigned int e = atomicAdd(&cnt[2*img+1], 1u);
      if (e < EQ_CAP) eqbuf[img*EQ_CAP + e] = (unsigned int)i;
    }
  }
}

// ---------------- finalize: pick R smallest-index ties, pad sort buffer ----------------
__global__ void k_finalize(const unsigned int* state, const unsigned int* cnt,
                           unsigned long long* sel, const unsigned int* eqbuf){
  int img = blockIdx.x;
  unsigned int R = state[2*img+1];
  unsigned int G = PRE_K - R;
  unsigned int T = state[2*img];
  unsigned int E = cnt[2*img+1]; if (E > EQ_CAP) E = EQ_CAP;
  if (threadIdx.x == 0){
    unsigned int last = 0; bool first = true;
    for (unsigned int r = 0; r < R; ++r){
      unsigned int best = 0xFFFFFFFFu;
      for (unsigned int e = 0; e < E; ++e){
        unsigned int v = eqbuf[img*EQ_CAP + e];
        if ((first || v > last) && v < best) best = v;
      }
      sel[(size_t)img*SORT_N + G + r] =
        ((unsigned long long)T << 32) | (unsigned long long)(~best);
      last = best; first = false;
    }
  }
  for (int i = PRE_K + threadIdx.x; i < SORT_N; i += blockDim.x)
    sel[(size_t)img*SORT_N + i] = 0ull;
}

// ---------------- bitonic sort 2048 u64 descending (score desc, idx asc) ----------------
__global__ void __launch_bounds__(1024) k_sort(unsigned long long* sel){
  __shared__ unsigned long long a[SORT_N];
  int img = blockIdx.x;
  for (int i = threadIdx.x; i < SORT_N; i += blockDim.x) a[i] = sel[(size_t)img*SORT_N + i];
  __syncthreads();
  for (int k = 2; k <= SORT_N; k <<= 1){
    for (int j = k >> 1; j > 0; j >>= 1){
      for (int i = threadIdx.x; i < SORT_N; i += blockDim.x){
        int ixj = i ^ j;
        if (ixj > i){
          bool up = ((i & k) == 0);
          unsigned long long x = a[i], y = a[ixj];
          if ((x < y) == up){ a[i] = y; a[ixj] = x; }  // descending sort
        }
      }
      __syncthreads();
    }
  }
  for (int i = threadIdx.x; i < SORT_N; i += blockDim.x) sel[(size_t)img*SORT_N + i] = a[i];
}

// ---------------- decode + clip + area/valid for the selected 2000 ----------------
__global__ void k_decode(const float* __restrict__ anchors, const float* __restrict__ obj,
                         const float* __restrict__ deltas, const unsigned long long* __restrict__ sel,
                         float* __restrict__ boxes, float* __restrict__ scores,
                         float* __restrict__ areas, unsigned int* __restrict__ valid){
  int img = blockIdx.y;
  int k = blockIdx.x * blockDim.x + threadIdx.x;
  if (k >= PRE_K) return;
  unsigned long long pk = sel[(size_t)img*SORT_N + k];
  unsigned int idx = ~(unsigned int)(pk & 0xFFFFFFFFull);
  float4 a = ((const float4*)anchors)[idx];
  float4 d = ((const float4*)deltas)[(size_t)img*N_ANCH + idx];
  float sc = obj[(size_t)img*N_ANCH + idx];

  float w  = rn_add(rn_sub(a.z, a.x), 1.0f);
  float h  = rn_add(rn_sub(a.w, a.y), 1.0f);
  float cx = rn_add(a.x, rn_mul(0.5f, w));
  float cy = rn_add(a.y, rn_mul(0.5f, h));
  float dw = fminf(d.z, DCLIP);
  float dh = fminf(d.w, DCLIP);
  float pcx = rn_add(rn_mul(d.x, w), cx);
  float pcy = rn_add(rn_mul(d.y, h), cy);
  float pw = rn_mul((float)exp((double)dw), w);   // correctly-rounded f32 exp
  float ph = rn_mul((float)exp((double)dh), h);
  float x1 = rn_sub(pcx, rn_mul(0.5f, pw));
  float y1 = rn_sub(pcy, rn_mul(0.5f, ph));
  float x2 = rn_sub(rn_add(pcx, rn_mul(0.5f, pw)), 1.0f);
  float y2 = rn_sub(rn_add(pcy, rn_mul(0.5f, ph)), 1.0f);
  x1 = fminf(fmaxf(x1, 0.0f), IMG_W_M1);
  x2 = fminf(fmaxf(x2, 0.0f), IMG_W_M1);
  y1 = fminf(fmaxf(y1, 0.0f), IMG_H_M1);
  y2 = fminf(fmaxf(y2, 0.0f), IMG_H_M1);
  float bw = rn_add(rn_sub(x2, x1), 1.0f);
  float bh = rn_add(rn_sub(y2, y1), 1.0f);
  ((float4*)boxes)[(size_t)img*PRE_K + k] = make_float4(x1, y1, x2, y2);
  scores[img*PRE_K + k] = sc;
  areas[img*PRE_K + k]  = rn_mul(bw, bh);
  valid[img*PRE_K + k]  = (bw >= 0.0f && bh >= 0.0f) ? 1u : 0u;
}

// ---------------- NMS suppression bitmask (upper triangle) ----------------
__global__ void k_mask(const float* __restrict__ boxes, const float* __restrict__ areas,
                       unsigned long long* __restrict__ mask){
  int jblk = blockIdx.x, iblk = blockIdx.y, img = blockIdx.z;
  if (jblk < iblk) return;
  __shared__ float4 jb[64];
  __shared__ float  ja[64];
  int tj = jblk*64 + threadIdx.x;
  if (tj < PRE_K){
    jb[threadIdx.x] = ((const float4*)boxes)[(size_t)img*PRE_K + tj];
    ja[threadIdx.x] = areas[img*PRE_K + tj];
  }
  __syncthreads();
  int i = iblk*64 + threadIdx.x;
  if (i >= PRE_K) return;
  float4 bi = ((const float4*)boxes)[(size_t)img*PRE_K + i];
  float ai = areas[img*PRE_K + i];
  unsigned long long bits = 0;
  int jmax = min(64, PRE_K - jblk*64);
  for (int b = 0; b < jmax; ++b){
    int j = jblk*64 + b;
    if (j <= i) continue;
    float4 bj = jb[b];
    if (iou_gt(bi.x,bi.y,bi.z,bi.w,ai, bj.x,bj.y,bj.z,bj.w,ja[b])) bits |= 1ull << b;
  }
  mask[((size_t)img*PRE_K + i)*NMS_WORDS + jblk] = bits;
}

// ---------------- pipelined greedy reduce + output pack ----------------
// Waves 1-8 stream 64-row mask chunks into a double-buffered LDS ring.
// Consumer wave exploits the strict upper-triangularity of the mask:
// within a chunk, row b's keep bit is final BEFORE step b, so one fused pass
// both resolves the chunk's 64 keep bits (replicated word k, diagonal-word
// broadcast reads) and accumulates each lane's remv-word update (acc).
// All intermediates are NAMED SCALARS -> guaranteed registers (rounds 2/3
// showed private arrays here were kept in scratch: +340 KB WRITE_SIZE on
// the serial critical path, 64-VGPR pin).
__global__ void __launch_bounds__(1024) k_nms_out(const unsigned long long* __restrict__ mask,
                          const unsigned int* __restrict__ valid,
                          const float* __restrict__ boxes, const float* __restrict__ scores,
                          float* __restrict__ out){
  __shared__ unsigned long long lbuf[2][64 * NMS_WORDS];  // 2 x 16 KB
  __shared__ unsigned long long keepw[NMS_WORDS];
  __shared__ unsigned int kpre[NMS_WORDS + 1];
  int img = blockIdx.x;
  int tid = threadIdx.x;
  const unsigned long long* mrow = mask + (size_t)img * PRE_K * NMS_WORDS;
  const int TOT_U64 = PRE_K * NMS_WORDS;  // 64000

  // consumer init: remv word per lane (<32): invalid/out-of-range bits pre-set
  unsigned long long remv = 0;
  if (tid < NMS_WORDS){
    for (int b = 0; b < 64; ++b){
      int i = tid*64 + b;
      bool ok = (i < PRE_K) && (valid[img*PRE_K + i] != 0u);
      if (!ok) remv |= 1ull << b;
    }
  }

  // prologue: load chunk 0 into lbuf[0]
  int lt = tid - 64;  // loader threads 64..575
  if (lt >= 0 && lt < 512){
    int e0 = lt * 4;
    ulonglong2 v0, v1; v0.x = v0.y = v1.x = v1.y = 0ull;
    if (e0 < TOT_U64){
      const ulonglong2* g = (const ulonglong2*)(mrow + e0);
      v0 = g[0]; v1 = g[1];
    }
    ulonglong2* l = (ulonglong2*)&lbuf[0][e0];
    l[0] = v0; l[1] = v1;
  }
  __syncthreads();

  for (int c = 0; c < NCHUNK; ++c){
    // loaders: fetch chunk c+1 into the other buffer
    if (lt >= 0 && lt < 512 && (c + 1) < NCHUNK){
      int e0 = lt * 4;
      int off = (c + 1) * (64 * NMS_WORDS) + e0;
      ulonglong2 v0, v1; v0.x = v0.y = v1.x = v1.y = 0ull;
      if (off < TOT_U64){
        const ulonglong2* g = (const ulonglong2*)(mrow + off);
        v0 = g[0]; v1 = g[1];
      }
      ulonglong2* l = (ulonglong2*)&lbuf[(c + 1) & 1][e0];
      l[0] = v0; l[1] = v1;
    }
    // consumer wave: fused resolve+apply over the 64 rows of chunk c
    if (tid < 64){
      const unsigned long long* B = &lbuf[c & 1][0];
      int w = tid;
      int wm = w & (NMS_WORDS - 1);                    // safe LDS column
      unsigned long long k = ~shfl_u64(remv, c);       // chunk keep bits (replicated)
      unsigned long long acc = 0;                      // this lane's remv-word update
      for (int s = 0; s < 64; s += 8){
        const unsigned long long* Br = B + (size_t)s * NMS_WORDS;
        unsigned long long dg0 = Br[0*NMS_WORDS + c], rw0 = Br[0*NMS_WORDS + wm];
        unsigned long long dg1 = Br[1*NMS_WORDS + c], rw1 = Br[1*NMS_WORDS + wm];
        unsigned long long dg2 = Br[2*NMS_WORDS + c], rw2 = Br[2*NMS_WORDS + wm];
        unsigned long long dg3 = Br[3*NMS_WORDS + c], rw3 = Br[3*NMS_WORDS + wm];
        unsigned long long dg4 = Br[4*NMS_WORDS + c], rw4 = Br[4*NMS_WORDS + wm];
        unsigned long long dg5 = Br[5*NMS_WORDS + c], rw5 = Br[5*NMS_WORDS + wm];
        unsigned long long dg6 = Br[6*NMS_WORDS + c], rw6 = Br[6*NMS_WORDS + wm];
        unsigned long long dg7 = Br[7*NMS_WORDS + c], rw7 = Br[7*NMS_WORDS + wm];
        unsigned long long m;
        m = ((k >> (s+0)) & 1ull) ? ~0ull : 0ull; k &= ~(dg0 & m); acc |= rw0 & m;
        m = ((k >> (s+1)) & 1ull) ? ~0ull : 0ull; k &= ~(dg1 & m); acc |= rw1 & m;
        m = ((k >> (s+2)) & 1ull) ? ~0ull : 0ull; k &= ~(dg2 & m); acc |= rw2 & m;
        m = ((k >> (s+3)) & 1ull) ? ~0ull : 0ull; k &= ~(dg3 & m); acc |= rw3 & m;
        m = ((k >> (s+4)) & 1ull) ? ~0ull : 0ull; k &= ~(dg4 & m); acc |= rw4 & m;
        m = ((k >> (s+5)) & 1ull) ? ~0ull : 0ull; k &= ~(dg5 & m); acc |= rw5 & m;
        m = ((k >> (s+6)) & 1ull) ? ~0ull : 0ull; k &= ~(dg6 & m); acc |= rw6 & m;
        m = ((k >> (s+7)) & 1ull) ? ~0ull : 0ull; k &= ~(dg7 & m); acc |= rw7 & m;
      }
      if (w == c)                     remv = ~k;       // this chunk's word: final
      else if (w > c && w < NMS_WORDS) remv |= acc;    // later words: accumulate
    }
    __syncthreads();
  }

  if (tid < NMS_WORDS) keepw[tid] = ~remv;
  __syncthreads();
  if (tid == 0){
    unsigned int s = 0;
    for (int w = 0; w < NMS_WORDS; ++w){ kpre[w] = s; s += __popcll(keepw[w]); }
    kpre[NMS_WORDS] = s;
  }
  __syncthreads();
  unsigned int nkept = kpre[NMS_WORDS];
  for (int i = tid; i < PRE_K; i += blockDim.x){
    int w = i >> 6, b = i & 63;
    unsigned long long kw = keepw[w];
    bool kept = (kw >> b) & 1ull;
    unsigned long long below = (b == 0) ? 0ull : (kw & ((~0ull) >> (64 - b)));
    unsigned int rank = kpre[w] + (unsigned int)__popcll(below);
    unsigned int pos = kept ? rank : (nkept + (unsigned int)i - rank);
    if (pos < POST_K){
      float4 bx = ((const float4*)boxes)[(size_t)img*PRE_K + i];
      float sc = kept ? scores[img*PRE_K + i] : -1e9f;
      float* o = out + ((size_t)img*POST_K + pos) * 5;
      o[0] = bx.x; o[1] = bx.y; o[2] = bx.z; o[3] = bx.w; o[4] = sc;
    }
  }
}

// ---------------- fallback: in-LDS sequential NMS (small ws) ----------------
__global__ void __launch_bounds__(1024) k_nms_seq(const unsigned int* __restrict__ valid,
                         const float* __restrict__ boxes, const float* __restrict__ areas,
                         const float* __restrict__ scores, float* __restrict__ out){
  __shared__ float4 bxs[PRE_K];
  __shared__ float  ars[PRE_K];
  __shared__ unsigned char kp[PRE_K];
  __shared__ unsigned long long keepw[NMS_WORDS];
  __shared__ unsigned int kpre[NMS_WORDS + 1];
  int img = blockIdx.x, tid = threadIdx.x;
  for (int i = tid; i < PRE_K; i += blockDim.x){
    bxs[i] = ((const float4*)boxes)[(size_t)img*PRE_K + i];
    ars[i] = areas[img*PRE_K + i];
    kp[i]  = (unsigned char)(valid[img*PRE_K + i] != 0u);
  }
  __syncthreads();
  for (int i = 0; i < PRE_K; ++i){
    if (kp[i]){
      float4 bi = bxs[i]; float ai = ars[i];
      for (int j = i + 1 + tid; j < PRE_K; j += blockDim.x){
        if (!kp[j]) continue;
        float4 bj = bxs[j];
        if (iou_gt(bi.x,bi.y,bi.z,bi.w,ai, bj.x,bj.y,bj.z,bj.w,ars[j])) kp[j] = 0;
      }
    }
    __syncthreads();
  }
  if (tid < NMS_WORDS){
    unsigned long long w = 0;
    for (int b = 0; b < 64; ++b){
      int i = tid*64 + b;
      if (i < PRE_K && kp[i]) w |= 1ull << b;
    }
    keepw[tid] = w;
  }
  __syncthreads();
  if (tid == 0){
    unsigned int s = 0;
    for (int w = 0; w < NMS_WORDS; ++w){ kpre[w] = s; s += __popcll(keepw[w]); }
    kpre[NMS_WORDS] = s;
  }
  __syncthreads();
  unsigned int nkept = kpre[NMS_WORDS];
  for (int i = tid; i < PRE_K; i += blockDim.x){
    int w = i >> 6, b = i & 63;
    unsigned long long kw = keepw[w];
    bool kept = (kw >> b) & 1ull;
    unsigned long long below = (b == 0) ? 0ull : (kw & ((~0ull) >> (64 - b)));
    unsigned int rank = kpre[w] + (unsigned int)__popcll(below);
    unsigned int pos = kept ? rank : (nkept + (unsigned int)i - rank);
    if (pos < POST_K){
      float4 bx = bxs[i];
      float sc = kept ? scores[img*PRE_K + i] : -1e9f;
      float* o = out + ((size_t)img*POST_K + pos) * 5;
      o[0] = bx.x; o[1] = bx.y; o[2] = bx.z; o[3] = bx.w; o[4] = sc;
    }
  }
}

extern "C" void kernel_launch(void* const* d_in, const int* in_sizes, int n_in,
                              void* d_out, int out_size, void* d_ws, size_t ws_size,
                              hipStream_t stream) {
  const float* anchors    = (const float*)d_in[0];
  const float* objectness = (const float*)d_in[1];
  const float* deltas     = (const float*)d_in[2];
  float* out = (float*)d_out;
  char* ws = (char*)d_ws;

  unsigned int* hist          = (unsigned int*)(ws + 0);        // 65536
  unsigned int* state         = (unsigned int*)(ws + 65536);    // 64
  unsigned int* cnt           = (unsigned int*)(ws + 65600);    // 64
  unsigned long long* sel     = (unsigned long long*)(ws + 65664);   // 131072
  unsigned int* eqbuf         = (unsigned int*)(ws + 196736);   // 131072
  float* boxes                = (float*)(ws + 327808);          // 256000 (16B aligned)
  float* scores               = (float*)(ws + 583808);          // 64000
  float* areas                = (float*)(ws + 647808);          // 64000
  unsigned int* valid         = (unsigned int*)(ws + 711808);   // 64000
  unsigned long long* mask    = (unsigned long long*)(ws + 775936); // 4096000
  size_t need_mask = 775936 + (size_t)N_IMG * PRE_K * NMS_WORDS * 8;

  hipLaunchKernelGGL(k_init, dim3(32), dim3(256), 0, stream, hist, state, cnt);

  const int shifts[3]   = {21, 10, 0};
  const int hishifts[3] = {32, 21, 10};
  for (int p = 0; p < 3; ++p){
    hipLaunchKernelGGL(k_hist, dim3(128, N_IMG), dim3(256), 0, stream,
                       objectness, hist, state, shifts[p], hishifts[p]);
    hipLaunchKernelGGL(k_scan, dim3(N_IMG), dim3(256), 0, stream, hist, state, shifts[p]);
  }
  hipLaunchKernelGGL(k_collect, dim3(128, N_IMG), dim3(256), 0, stream,
                     objectness, state, cnt, sel, eqbuf);
  hipLaunchKernelGGL(k_finalize, dim3(N_IMG), dim3(256), 0, stream, state, cnt, sel, eqbuf);
  hipLaunchKernelGGL(k_sort, dim3(N_IMG), dim3(1024), 0, stream, sel);
  hipLaunchKernelGGL(k_decode, dim3((PRE_K + 255)/256, N_IMG), dim3(256), 0, stream,
                     anchors, objectness, deltas, sel, boxes, scores, areas, valid);

  if (ws_size >= need_mask){
    hipLaunchKernelGGL(k_mask, dim3(NMS_WORDS, NMS_WORDS, N_IMG), dim3(64), 0, stream,
                       boxes, areas, mask);
    hipLaunchKernelGGL(k_nms_out, dim3(N_IMG), dim3(1024), 0, stream,
                       mask, valid, boxes, scores, out);
  } else {
    hipLaunchKernelGGL(k_nms_seq, dim3(N_IMG), dim3(1024), 0, stream,
                       valid, boxes, areas, scores, out);
  }
}

// Round 5
// 303.918 us; speedup vs baseline: 2.1446x; 1.4070x over previous
//
#include <hip/hip_runtime.h>
#include <math.h>

#define N_IMG 8
#define N_ANCH 250000
#define PRE_K 2000
#define POST_K 1000
#define SORT_N 2048
#define EQ_CAP 4096
#define NMS_WORDS 32   // ceil(2000/64)
#define NCHUNK 32      // ceil(2000/64) row-chunks of 64
#define CNT_STRIDE 64  // uints per image: 256B -> private cacheline per image

#define IMG_W_M1 1332.0f
#define IMG_H_M1 799.0f
#define DCLIP 4.135166556742356f
#define NMS_T 0.7f

__device__ __forceinline__ float rn_add(float a, float b){ return __fadd_rn(a,b); }
__device__ __forceinline__ float rn_sub(float a, float b){ return __fsub_rn(a,b); }
__device__ __forceinline__ float rn_mul(float a, float b){ return __fmul_rn(a,b); }
__device__ __forceinline__ float rn_div(float a, float b){ return __fdiv_rn(a,b); }

// monotonic float->uint mapping (order-preserving, larger float -> larger uint)
__device__ __forceinline__ unsigned int mono_of(float f){
  unsigned int u = __float_as_uint(f);
  return u ^ ((u >> 31) ? 0xFFFFFFFFu : 0x80000000u);
}

__device__ __forceinline__ unsigned long long shfl_u64(unsigned long long v, int lane){
  int lo = __shfl((int)(unsigned int)(v & 0xFFFFFFFFull), lane, 64);
  int hi = __shfl((int)(unsigned int)(v >> 32), lane, 64);
  return ((unsigned long long)(unsigned int)hi << 32) | (unsigned long long)(unsigned int)lo;
}

// exact-op-order IoU > 0.7 test (mirrors reference float32 op sequence)
__device__ __forceinline__ bool iou_gt(float x1,float y1,float x2,float y2,float a1,
                                       float X1,float Y1,float X2,float Y2,float a2){
  float ltx = fmaxf(x1, X1), lty = fmaxf(y1, Y1);
  float rbx = fminf(x2, X2), rby = fminf(y2, Y2);
  float wx = fmaxf(rn_add(rn_sub(rbx, ltx), 1.0f), 0.0f);
  float wy = fmaxf(rn_add(rn_sub(rby, lty), 1.0f), 0.0f);
  float inter = rn_mul(wx, wy);
  float iou = rn_div(inter, rn_sub(rn_add(a1, a2), inter));
  return iou > NMS_T;
}

// ---------------- kernel 0: init ws state ----------------
__global__ void k_init(unsigned int* hist, unsigned int* state, unsigned int* cnt){
  int t = blockIdx.x * blockDim.x + threadIdx.x;
  int tot = N_IMG * 2048;
  for (int i = t; i < tot; i += gridDim.x * blockDim.x) hist[i] = 0;
  if (t < N_IMG * CNT_STRIDE) cnt[t] = 0;
  if (t < N_IMG){
    state[2*t] = 0;          // prefix
    state[2*t+1] = PRE_K;    // remaining
  }
}

// ---------------- radix-select histogram pass ----------------
__global__ void k_hist(const float* __restrict__ obj, unsigned int* __restrict__ hist,
                       const unsigned int* __restrict__ state, int shift, int hishift){
  __shared__ unsigned int lh[2048];
  int img = blockIdx.y;
  for (int i = threadIdx.x; i < 2048; i += blockDim.x) lh[i] = 0;
  __syncthreads();
  unsigned int prefix = state[2*img];
  unsigned int phi = (hishift >= 32) ? 0u : (prefix >> hishift);
  const float* o = obj + (size_t)img * N_ANCH;
  int stride = gridDim.x * blockDim.x;
  for (int i = blockIdx.x * blockDim.x + threadIdx.x; i < N_ANCH; i += stride){
    unsigned int key = mono_of(o[i]);
    bool ok = (hishift >= 32) || ((key >> hishift) == phi);
    if (ok) atomicAdd(&lh[(key >> shift) & 2047], 1u);
  }
  __syncthreads();
  for (int i = threadIdx.x; i < 2048; i += blockDim.x)
    if (lh[i]) atomicAdd(&hist[img*2048 + i], lh[i]);
}

// ---------------- radix-select scan pass (also zeros hist for next pass) ----------------
__global__ void k_scan(unsigned int* hist, unsigned int* state, int shift){
  int img = blockIdx.x;
  unsigned int* h = hist + img * 2048;
  if (threadIdx.x == 0){
    unsigned int remaining = state[2*img+1];
    unsigned int prefix = state[2*img];
    unsigned int cum = 0;
    for (int d = 2047; d >= 0; --d){
      unsigned int c = h[d];
      if (cum + c >= remaining){
        prefix |= ((unsigned int)d) << shift;
        remaining -= cum;
        break;
      }
      cum += c;
    }
    state[2*img] = prefix;
    state[2*img+1] = remaining;
  }
  __syncthreads();
  for (int i = threadIdx.x; i < 2048; i += blockDim.x) h[i] = 0;
}

// ---------------- collect: keys > T into sel, keys == T into eqbuf ----------------
// Wave-aggregated atomics (round-4 profile: per-thread same-line atomics
// serialized the whole dispatch at 145 us with all pipes <0.5% busy).
// One atomicAdd per wave per hit-category; slot order is arbitrary but the
// subsequent full sort of sel[] makes the output invariant to it.
__global__ void k_collect(const float* __restrict__ obj, const unsigned int* __restrict__ state,
                          unsigned int* cnt, unsigned long long* sel, unsigned int* eqbuf){
  int img = blockIdx.y;
  unsigned int T = state[2*img];
  const float* o = obj + (size_t)img * N_ANCH;
  int stride = gridDim.x * blockDim.x;
  int lane = threadIdx.x & 63;
  unsigned long long below = (lane == 0) ? 0ull : ((~0ull) >> (64 - lane));
  for (int i = blockIdx.x * blockDim.x + threadIdx.x; i < N_ANCH; i += stride){
    unsigned int key = mono_of(o[i]);
    bool gt = key > T;
    bool eq = key == T;
    unsigned long long bgt = __ballot(gt);
    if (bgt){
      int leader = (int)(__ffsll((long long)bgt) - 1);
      unsigned int base = 0;
      if (lane == leader) base = atomicAdd(&cnt[img*CNT_STRIDE], (unsigned int)__popcll(bgt));
      base = (unsigned int)__shfl((int)base, leader, 64);
      if (gt){
        unsigned int slot = base + (unsigned int)__popcll(bgt & below);
        if (slot < PRE_K)
          sel[(size_t)img*SORT_N + slot] =
            ((unsigned long long)key << 32) | (unsigned long long)(~(unsigned int)i);
      }
    }
    unsigned long long beq = __ballot(eq);
    if (beq){
      int leader = (int)(__ffsll((long long)beq) - 1);
      unsigned int base = 0;
      if (lane == leader) base = atomicAdd(&cnt[img*CNT_STRIDE + 1], (unsigned int)__popcll(beq));
      base = (unsigned int)__shfl((int)base, leader, 64);
      if (eq){
        unsigned int e = base + (unsigned int)__popcll(beq & below);
        if (e < EQ_CAP) eqbuf[img*EQ_CAP + e] = (unsigned int)i;
      }
    }
  }
}

// ---------------- finalize: pick R smallest-index ties, pad sort buffer ----------------
__global__ void k_finalize(const unsigned int* state, const unsigned int* cnt,
                           unsigned long long* sel, const unsigned int* eqbuf){
  int img = blockIdx.x;
  unsigned int R = state[2*img+1];
  unsigned int G = PRE_K - R;
  unsigned int T = state[2*img];
  unsigned int E = cnt[img*CNT_STRIDE + 1]; if (E > EQ_CAP) E = EQ_CAP;
  if (threadIdx.x == 0){
    unsigned int last = 0; bool first = true;
    for (unsigned int r = 0; r < R; ++r){
      unsigned int best = 0xFFFFFFFFu;
      for (unsigned int e = 0; e < E; ++e){
        unsigned int v = eqbuf[img*EQ_CAP + e];
        if ((first || v > last) && v < best) best = v;
      }
      sel[(size_t)img*SORT_N + G + r] =
        ((unsigned long long)T << 32) | (unsigned long long)(~best);
      last = best; first = false;
    }
  }
  for (int i = PRE_K + threadIdx.x; i < SORT_N; i += blockDim.x)
    sel[(size_t)img*SORT_N + i] = 0ull;
}

// ---------------- bitonic sort 2048 u64 descending (score desc, idx asc) ----------------
__global__ void __launch_bounds__(1024) k_sort(unsigned long long* sel){
  __shared__ unsigned long long a[SORT_N];
  int img = blockIdx.x;
  for (int i = threadIdx.x; i < SORT_N; i += blockDim.x) a[i] = sel[(size_t)img*SORT_N + i];
  __syncthreads();
  for (int k = 2; k <= SORT_N; k <<= 1){
    for (int j = k >> 1; j > 0; j >>= 1){
      for (int i = threadIdx.x; i < SORT_N; i += blockDim.x){
        int ixj = i ^ j;
        if (ixj > i){
          bool up = ((i & k) == 0);
          unsigned long long x = a[i], y = a[ixj];
          if ((x < y) == up){ a[i] = y; a[ixj] = x; }  // descending sort
        }
      }
      __syncthreads();
    }
  }
  for (int i = threadIdx.x; i < SORT_N; i += blockDim.x) sel[(size_t)img*SORT_N + i] = a[i];
}

// ---------------- decode + clip + area/valid for the selected 2000 ----------------
__global__ void k_decode(const float* __restrict__ anchors, const float* __restrict__ obj,
                         const float* __restrict__ deltas, const unsigned long long* __restrict__ sel,
                         float* __restrict__ boxes, float* __restrict__ scores,
                         float* __restrict__ areas, unsigned int* __restrict__ valid){
  int img = blockIdx.y;
  int k = blockIdx.x * blockDim.x + threadIdx.x;
  if (k >= PRE_K) return;
  unsigned long long pk = sel[(size_t)img*SORT_N + k];
  unsigned int idx = ~(unsigned int)(pk & 0xFFFFFFFFull);
  float4 a = ((const float4*)anchors)[idx];
  float4 d = ((const float4*)deltas)[(size_t)img*N_ANCH + idx];
  float sc = obj[(size_t)img*N_ANCH + idx];

  float w  = rn_add(rn_sub(a.z, a.x), 1.0f);
  float h  = rn_add(rn_sub(a.w, a.y), 1.0f);
  float cx = rn_add(a.x, rn_mul(0.5f, w));
  float cy = rn_add(a.y, rn_mul(0.5f, h));
  float dw = fminf(d.z, DCLIP);
  float dh = fminf(d.w, DCLIP);
  float pcx = rn_add(rn_mul(d.x, w), cx);
  float pcy = rn_add(rn_mul(d.y, h), cy);
  float pw = rn_mul((float)exp((double)dw), w);   // correctly-rounded f32 exp
  float ph = rn_mul((float)exp((double)dh), h);
  float x1 = rn_sub(pcx, rn_mul(0.5f, pw));
  float y1 = rn_sub(pcy, rn_mul(0.5f, ph));
  float x2 = rn_sub(rn_add(pcx, rn_mul(0.5f, pw)), 1.0f);
  float y2 = rn_sub(rn_add(pcy, rn_mul(0.5f, ph)), 1.0f);
  x1 = fminf(fmaxf(x1, 0.0f), IMG_W_M1);
  x2 = fminf(fmaxf(x2, 0.0f), IMG_W_M1);
  y1 = fminf(fmaxf(y1, 0.0f), IMG_H_M1);
  y2 = fminf(fmaxf(y2, 0.0f), IMG_H_M1);
  float bw = rn_add(rn_sub(x2, x1), 1.0f);
  float bh = rn_add(rn_sub(y2, y1), 1.0f);
  ((float4*)boxes)[(size_t)img*PRE_K + k] = make_float4(x1, y1, x2, y2);
  scores[img*PRE_K + k] = sc;
  areas[img*PRE_K + k]  = rn_mul(bw, bh);
  valid[img*PRE_K + k]  = (bw >= 0.0f && bh >= 0.0f) ? 1u : 0u;
}

// ---------------- NMS suppression bitmask (upper triangle) ----------------
__global__ void k_mask(const float* __restrict__ boxes, const float* __restrict__ areas,
                       unsigned long long* __restrict__ mask){
  int jblk = blockIdx.x, iblk = blockIdx.y, img = blockIdx.z;
  if (jblk < iblk) return;
  __shared__ float4 jb[64];
  __shared__ float  ja[64];
  int tj = jblk*64 + threadIdx.x;
  if (tj < PRE_K){
    jb[threadIdx.x] = ((const float4*)boxes)[(size_t)img*PRE_K + tj];
    ja[threadIdx.x] = areas[img*PRE_K + tj];
  }
  __syncthreads();
  int i = iblk*64 + threadIdx.x;
  if (i >= PRE_K) return;
  float4 bi = ((const float4*)boxes)[(size_t)img*PRE_K + i];
  float ai = areas[img*PRE_K + i];
  unsigned long long bits = 0;
  int jmax = min(64, PRE_K - jblk*64);
  for (int b = 0; b < jmax; ++b){
    int j = jblk*64 + b;
    if (j <= i) continue;
    float4 bj = jb[b];
    if (iou_gt(bi.x,bi.y,bi.z,bi.w,ai, bj.x,bj.y,bj.z,bj.w,ja[b])) bits |= 1ull << b;
  }
  mask[((size_t)img*PRE_K + i)*NMS_WORDS + jblk] = bits;
}

// ---------------- pipelined greedy reduce + output pack ----------------
// Waves 1-8 stream 64-row mask chunks into a double-buffered LDS ring.
// Consumer wave exploits the strict upper-triangularity of the mask:
// within a chunk, row b's keep bit is final BEFORE step b, so one fused pass
// both resolves the chunk's 64 keep bits (replicated word k, diagonal-word
// broadcast reads) and accumulates each lane's remv-word update (acc).
// All intermediates are NAMED SCALARS -> guaranteed registers (rounds 2/3
// showed private arrays here were kept in scratch: +340 KB WRITE_SIZE on
// the serial critical path, 64-VGPR pin).
__global__ void __launch_bounds__(1024) k_nms_out(const unsigned long long* __restrict__ mask,
                          const unsigned int* __restrict__ valid,
                          const float* __restrict__ boxes, const float* __restrict__ scores,
                          float* __restrict__ out){
  __shared__ unsigned long long lbuf[2][64 * NMS_WORDS];  // 2 x 16 KB
  __shared__ unsigned long long keepw[NMS_WORDS];
  __shared__ unsigned int kpre[NMS_WORDS + 1];
  int img = blockIdx.x;
  int tid = threadIdx.x;
  const unsigned long long* mrow = mask + (size_t)img * PRE_K * NMS_WORDS;
  const int TOT_U64 = PRE_K * NMS_WORDS;  // 64000

  // consumer init: remv word per lane (<32): invalid/out-of-range bits pre-set
  unsigned long long remv = 0;
  if (tid < NMS_WORDS){
    for (int b = 0; b < 64; ++b){
      int i = tid*64 + b;
      bool ok = (i < PRE_K) && (valid[img*PRE_K + i] != 0u);
      if (!ok) remv |= 1ull << b;
    }
  }

  // prologue: load chunk 0 into lbuf[0]
  int lt = tid - 64;  // loader threads 64..575
  if (lt >= 0 && lt < 512){
    int e0 = lt * 4;
    ulonglong2 v0, v1; v0.x = v0.y = v1.x = v1.y = 0ull;
    if (e0 < TOT_U64){
      const ulonglong2* g = (const ulonglong2*)(mrow + e0);
      v0 = g[0]; v1 = g[1];
    }
    ulonglong2* l = (ulonglong2*)&lbuf[0][e0];
    l[0] = v0; l[1] = v1;
  }
  __syncthreads();

  for (int c = 0; c < NCHUNK; ++c){
    // loaders: fetch chunk c+1 into the other buffer
    if (lt >= 0 && lt < 512 && (c + 1) < NCHUNK){
      int e0 = lt * 4;
      int off = (c + 1) * (64 * NMS_WORDS) + e0;
      ulonglong2 v0, v1; v0.x = v0.y = v1.x = v1.y = 0ull;
      if (off < TOT_U64){
        const ulonglong2* g = (const ulonglong2*)(mrow + off);
        v0 = g[0]; v1 = g[1];
      }
      ulonglong2* l = (ulonglong2*)&lbuf[(c + 1) & 1][e0];
      l[0] = v0; l[1] = v1;
    }
    // consumer wave: fused resolve+apply over the 64 rows of chunk c
    if (tid < 64){
      const unsigned long long* B = &lbuf[c & 1][0];
      int w = tid;
      int wm = w & (NMS_WORDS - 1);                    // safe LDS column
      unsigned long long k = ~shfl_u64(remv, c);       // chunk keep bits (replicated)
      unsigned long long acc = 0;                      // this lane's remv-word update
      for (int s = 0; s < 64; s += 8){
        const unsigned long long* Br = B + (size_t)s * NMS_WORDS;
        unsigned long long dg0 = Br[0*NMS_WORDS + c], rw0 = Br[0*NMS_WORDS + wm];
        unsigned long long dg1 = Br[1*NMS_WORDS + c], rw1 = Br[1*NMS_WORDS + wm];
        unsigned long long dg2 = Br[2*NMS_WORDS + c], rw2 = Br[2*NMS_WORDS + wm];
        unsigned long long dg3 = Br[3*NMS_WORDS + c], rw3 = Br[3*NMS_WORDS + wm];
        unsigned long long dg4 = Br[4*NMS_WORDS + c], rw4 = Br[4*NMS_WORDS + wm];
        unsigned long long dg5 = Br[5*NMS_WORDS + c], rw5 = Br[5*NMS_WORDS + wm];
        unsigned long long dg6 = Br[6*NMS_WORDS + c], rw6 = Br[6*NMS_WORDS + wm];
        unsigned long long dg7 = Br[7*NMS_WORDS + c], rw7 = Br[7*NMS_WORDS + wm];
        unsigned long long m;
        m = ((k >> (s+0)) & 1ull) ? ~0ull : 0ull; k &= ~(dg0 & m); acc |= rw0 & m;
        m = ((k >> (s+1)) & 1ull) ? ~0ull : 0ull; k &= ~(dg1 & m); acc |= rw1 & m;
        m = ((k >> (s+2)) & 1ull) ? ~0ull : 0ull; k &= ~(dg2 & m); acc |= rw2 & m;
        m = ((k >> (s+3)) & 1ull) ? ~0ull : 0ull; k &= ~(dg3 & m); acc |= rw3 & m;
        m = ((k >> (s+4)) & 1ull) ? ~0ull : 0ull; k &= ~(dg4 & m); acc |= rw4 & m;
        m = ((k >> (s+5)) & 1ull) ? ~0ull : 0ull; k &= ~(dg5 & m); acc |= rw5 & m;
        m = ((k >> (s+6)) & 1ull) ? ~0ull : 0ull; k &= ~(dg6 & m); acc |= rw6 & m;
        m = ((k >> (s+7)) & 1ull) ? ~0ull : 0ull; k &= ~(dg7 & m); acc |= rw7 & m;
      }
      if (w == c)                     remv = ~k;       // this chunk's word: final
      else if (w > c && w < NMS_WORDS) remv |= acc;    // later words: accumulate
    }
    __syncthreads();
  }

  if (tid < NMS_WORDS) keepw[tid] = ~remv;
  __syncthreads();
  if (tid == 0){
    unsigned int s = 0;
    for (int w = 0; w < NMS_WORDS; ++w){ kpre[w] = s; s += __popcll(keepw[w]); }
    kpre[NMS_WORDS] = s;
  }
  __syncthreads();
  unsigned int nkept = kpre[NMS_WORDS];
  for (int i = tid; i < PRE_K; i += blockDim.x){
    int w = i >> 6, b = i & 63;
    unsigned long long kw = keepw[w];
    bool kept = (kw >> b) & 1ull;
    unsigned long long below = (b == 0) ? 0ull : (kw & ((~0ull) >> (64 - b)));
    unsigned int rank = kpre[w] + (unsigned int)__popcll(below);
    unsigned int pos = kept ? rank : (nkept + (unsigned int)i - rank);
    if (pos < POST_K){
      float4 bx = ((const float4*)boxes)[(size_t)img*PRE_K + i];
      float sc = kept ? scores[img*PRE_K + i] : -1e9f;
      float* o = out + ((size_t)img*POST_K + pos) * 5;
      o[0] = bx.x; o[1] = bx.y; o[2] = bx.z; o[3] = bx.w; o[4] = sc;
    }
  }
}

// ---------------- fallback: in-LDS sequential NMS (small ws) ----------------
__global__ void __launch_bounds__(1024) k_nms_seq(const unsigned int* __restrict__ valid,
                         const float* __restrict__ boxes, const float* __restrict__ areas,
                         const float* __restrict__ scores, float* __restrict__ out){
  __shared__ float4 bxs[PRE_K];
  __shared__ float  ars[PRE_K];
  __shared__ unsigned char kp[PRE_K];
  __shared__ unsigned long long keepw[NMS_WORDS];
  __shared__ unsigned int kpre[NMS_WORDS + 1];
  int img = blockIdx.x, tid = threadIdx.x;
  for (int i = tid; i < PRE_K; i += blockDim.x){
    bxs[i] = ((const float4*)boxes)[(size_t)img*PRE_K + i];
    ars[i] = areas[img*PRE_K + i];
    kp[i]  = (unsigned char)(valid[img*PRE_K + i] != 0u);
  }
  __syncthreads();
  for (int i = 0; i < PRE_K; ++i){
    if (kp[i]){
      float4 bi = bxs[i]; float ai = ars[i];
      for (int j = i + 1 + tid; j < PRE_K; j += blockDim.x){
        if (!kp[j]) continue;
        float4 bj = bxs[j];
        if (iou_gt(bi.x,bi.y,bi.z,bi.w,ai, bj.x,bj.y,bj.z,bj.w,ars[j])) kp[j] = 0;
      }
    }
    __syncthreads();
  }
  if (tid < NMS_WORDS){
    unsigned long long w = 0;
    for (int b = 0; b < 64; ++b){
      int i = tid*64 + b;
      if (i < PRE_K && kp[i]) w |= 1ull << b;
    }
    keepw[tid] = w;
  }
  __syncthreads();
  if (tid == 0){
    unsigned int s = 0;
    for (int w = 0; w < NMS_WORDS; ++w){ kpre[w] = s; s += __popcll(keepw[w]); }
    kpre[NMS_WORDS] = s;
  }
  __syncthreads();
  unsigned int nkept = kpre[NMS_WORDS];
  for (int i = tid; i < PRE_K; i += blockDim.x){
    int w = i >> 6, b = i & 63;
    unsigned long long kw = keepw[w];
    bool kept = (kw >> b) & 1ull;
    unsigned long long below = (b == 0) ? 0ull : (kw & ((~0ull) >> (64 - b)));
    unsigned int rank = kpre[w] + (unsigned int)__popcll(below);
    unsigned int pos = kept ? rank : (nkept + (unsigned int)i - rank);
    if (pos < POST_K){
      float4 bx = bxs[i];
      float sc = kept ? scores[img*PRE_K + i] : -1e9f;
      float* o = out + ((size_t)img*POST_K + pos) * 5;
      o[0] = bx.x; o[1] = bx.y; o[2] = bx.z; o[3] = bx.w; o[4] = sc;
    }
  }
}

extern "C" void kernel_launch(void* const* d_in, const int* in_sizes, int n_in,
                              void* d_out, int out_size, void* d_ws, size_t ws_size,
                              hipStream_t stream) {
  const float* anchors    = (const float*)d_in[0];
  const float* objectness = (const float*)d_in[1];
  const float* deltas     = (const float*)d_in[2];
  float* out = (float*)d_out;
  char* ws = (char*)d_ws;

  unsigned int* hist          = (unsigned int*)(ws + 0);        // 65536
  unsigned int* state         = (unsigned int*)(ws + 65536);    // 64
  unsigned int* cnt           = (unsigned int*)(ws + 65664);    // 2048 (256B/img)
  unsigned long long* sel     = (unsigned long long*)(ws + 67712);   // 131072
  unsigned int* eqbuf         = (unsigned int*)(ws + 198784);   // 131072
  float* boxes                = (float*)(ws + 329856);          // 256000 (16B aligned)
  float* scores               = (float*)(ws + 585856);          // 64000
  float* areas                = (float*)(ws + 649856);          // 64000
  unsigned int* valid         = (unsigned int*)(ws + 713856);   // 64000
  unsigned long long* mask    = (unsigned long long*)(ws + 777856); // 4096000
  size_t need_mask = 777856 + (size_t)N_IMG * PRE_K * NMS_WORDS * 8;

  hipLaunchKernelGGL(k_init, dim3(32), dim3(256), 0, stream, hist, state, cnt);

  const int shifts[3]   = {21, 10, 0};
  const int hishifts[3] = {32, 21, 10};
  for (int p = 0; p < 3; ++p){
    hipLaunchKernelGGL(k_hist, dim3(128, N_IMG), dim3(256), 0, stream,
                       objectness, hist, state, shifts[p], hishifts[p]);
    hipLaunchKernelGGL(k_scan, dim3(N_IMG), dim3(256), 0, stream, hist, state, shifts[p]);
  }
  hipLaunchKernelGGL(k_collect, dim3(128, N_IMG), dim3(256), 0, stream,
                     objectness, state, cnt, sel, eqbuf);
  hipLaunchKernelGGL(k_finalize, dim3(N_IMG), dim3(256), 0, stream, state, cnt, sel, eqbuf);
  hipLaunchKernelGGL(k_sort, dim3(N_IMG), dim3(1024), 0, stream, sel);
  hipLaunchKernelGGL(k_decode, dim3((PRE_K + 255)/256, N_IMG), dim3(256), 0, stream,
                     anchors, objectness, deltas, sel, boxes, scores, areas, valid);

  if (ws_size >= need_mask){
    hipLaunchKernelGGL(k_mask, dim3(NMS_WORDS, NMS_WORDS, N_IMG), dim3(64), 0, stream,
                       boxes, areas, mask);
    hipLaunchKernelGGL(k_nms_out, dim3(N_IMG), dim3(1024), 0, stream,
                       mask, valid, boxes, scores, out);
  } else {
    hipLaunchKernelGGL(k_nms_seq, dim3(N_IMG), dim3(1024), 0, stream,
                       valid, boxes, areas, scores, out);
  }
}

// Round 6
// 249.014 us; speedup vs baseline: 2.6174x; 1.2205x over previous
//
#include <hip/hip_runtime.h>
#include <math.h>

#define N_IMG 8
#define N_ANCH 250000
#define PRE_K 2000
#define POST_K 1000
#define SORT_N 2048
#define CAND_CAP 8192  // >= G + boundary-bin count (expected ~5.7K, ~39 sigma margin)
#define NMS_WORDS 32   // ceil(2000/64)
#define NCHUNK 32      // ceil(2000/64) row-chunks of 64
#define CNT_STRIDE 64  // uints per image: 256B -> private cacheline per image

#define IMG_W_M1 1332.0f
#define IMG_H_M1 799.0f
#define DCLIP 4.135166556742356f
#define NMS_T 0.7f

__device__ __forceinline__ float rn_add(float a, float b){ return __fadd_rn(a,b); }
__device__ __forceinline__ float rn_sub(float a, float b){ return __fsub_rn(a,b); }
__device__ __forceinline__ float rn_mul(float a, float b){ return __fmul_rn(a,b); }
__device__ __forceinline__ float rn_div(float a, float b){ return __fdiv_rn(a,b); }

// monotonic float->uint mapping (order-preserving, larger float -> larger uint)
__device__ __forceinline__ unsigned int mono_of(float f){
  unsigned int u = __float_as_uint(f);
  return u ^ ((u >> 31) ? 0xFFFFFFFFu : 0x80000000u);
}

__device__ __forceinline__ unsigned long long shfl_u64(unsigned long long v, int lane){
  int lo = __shfl((int)(unsigned int)(v & 0xFFFFFFFFull), lane, 64);
  int hi = __shfl((int)(unsigned int)(v >> 32), lane, 64);
  return ((unsigned long long)(unsigned int)hi << 32) | (unsigned long long)(unsigned int)lo;
}

// exact-op-order IoU > 0.7 test (mirrors reference float32 op sequence)
__device__ __forceinline__ bool iou_gt(float x1,float y1,float x2,float y2,float a1,
                                       float X1,float Y1,float X2,float Y2,float a2){
  float ltx = fmaxf(x1, X1), lty = fmaxf(y1, Y1);
  float rbx = fminf(x2, X2), rby = fminf(y2, Y2);
  float wx = fmaxf(rn_add(rn_sub(rbx, ltx), 1.0f), 0.0f);
  float wy = fmaxf(rn_add(rn_sub(rby, lty), 1.0f), 0.0f);
  float inter = rn_mul(wx, wy);
  float iou = rn_div(inter, rn_sub(rn_add(a1, a2), inter));
  return iou > NMS_T;
}

// ---------------- init: zero hist + cnt ----------------
__global__ void k_init(unsigned int* hist, unsigned int* cnt){
  int t = blockIdx.x * blockDim.x + threadIdx.x;
  for (int i = t; i < N_IMG * 2048; i += gridDim.x * blockDim.x) hist[i] = 0;
  if (t < N_IMG * CNT_STRIDE) cnt[t] = 0;
}

// ---------------- single coarse histogram (top 11 bits), float4 loads ----------------
__global__ void k_hist(const float* __restrict__ obj, unsigned int* __restrict__ hist){
  __shared__ unsigned int lh[2048];
  int img = blockIdx.y;
  for (int i = threadIdx.x; i < 2048; i += blockDim.x) lh[i] = 0;
  __syncthreads();
  const float4* o4 = (const float4*)(obj + (size_t)img * N_ANCH);
  int stride = gridDim.x * blockDim.x;
  for (int i = blockIdx.x * blockDim.x + threadIdx.x; i < N_ANCH/4; i += stride){
    float4 v = o4[i];
    atomicAdd(&lh[mono_of(v.x) >> 21], 1u);
    atomicAdd(&lh[mono_of(v.y) >> 21], 1u);
    atomicAdd(&lh[mono_of(v.z) >> 21], 1u);
    atomicAdd(&lh[mono_of(v.w) >> 21], 1u);
  }
  __syncthreads();
  for (int i = threadIdx.x; i < 2048; i += blockDim.x)
    if (lh[i]) atomicAdd(&hist[img*2048 + i], lh[i]);
}

// ---------------- find boundary bin (few-iteration serial scan) ----------------
__global__ void k_scan(const unsigned int* __restrict__ hist, unsigned int* state){
  int img = blockIdx.x;
  if (threadIdx.x == 0){
    const unsigned int* h = hist + img * 2048;
    unsigned int cum = 0; int d;
    for (d = 2047; d >= 0; --d){ cum += h[d]; if (cum >= PRE_K) break; }
    state[img] = (unsigned int)d;
  }
}

// ---------------- collect candidates: top-11 bits >= boundary bin ----------------
// wave-aggregated atomics (round-4 lesson: per-thread same-line atomics
// serialize the dispatch); slot order arbitrary, later select+sort fixes order.
__global__ void k_cand(const float* __restrict__ obj, const unsigned int* __restrict__ state,
                       unsigned int* cnt, unsigned long long* __restrict__ cand){
  int img = blockIdx.y;
  unsigned int bin = state[img];
  const float4* o4 = (const float4*)(obj + (size_t)img * N_ANCH);
  int stride = gridDim.x * blockDim.x;
  int lane = threadIdx.x & 63;
  unsigned long long below = (lane == 0) ? 0ull : ((~0ull) >> (64 - lane));
  for (int i = blockIdx.x * blockDim.x + threadIdx.x; i < N_ANCH/4; i += stride){
    float4 v = o4[i];
    #pragma unroll
    for (int s = 0; s < 4; ++s){
      float f = (s==0) ? v.x : (s==1) ? v.y : (s==2) ? v.z : v.w;
      unsigned int key = mono_of(f);
      bool hit = (key >> 21) >= bin;
      unsigned long long b = __ballot(hit);
      if (b){
        int leader = (int)(__ffsll((long long)b) - 1);
        unsigned int base = 0;
        if (lane == leader) base = atomicAdd(&cnt[img*CNT_STRIDE], (unsigned int)__popcll(b));
        base = (unsigned int)__shfl((int)base, leader, 64);
        if (hit){
          unsigned int slot = base + (unsigned int)__popcll(b & below);
          if (slot < CAND_CAP)
            cand[(size_t)img*CAND_CAP + slot] =
              ((unsigned long long)key << 32) | (unsigned long long)(~(unsigned int)(i*4 + s));
        }
      }
    }
  }
}

// ---------------- per-image: exact radix select + tie rule + sort + decode ----------------
// Replaces hist passes 2-3, scans 2-3, k_collect, k_finalize, k_sort, k_decode.
__global__ void __launch_bounds__(1024) k_selsort(
    const unsigned long long* __restrict__ cand, const unsigned int* __restrict__ cnt,
    const float* __restrict__ anchors, const float* __restrict__ deltas,
    float* __restrict__ boxes, float* __restrict__ scores,
    float* __restrict__ areas, unsigned int* __restrict__ valid){
  __shared__ unsigned long long sel_l[SORT_N];  // 16 KB
  __shared__ unsigned int bins[2048];           // 8 KB
  __shared__ unsigned int scal[4];              // rem, bin, cgt, ceq
  int img = blockIdx.x, tid = threadIdx.x;
  unsigned int n = cnt[img*CNT_STRIDE]; if (n > CAND_CAP) n = CAND_CAP;
  const unsigned long long* cd = cand + (size_t)img*CAND_CAP;

  unsigned int rem = PRE_K, prefix = 0;
  #pragma unroll
  for (int p = 0; p < 3; ++p){
    int shift  = (p==0) ? 21 : (p==1) ? 10 : 0;
    int mshift = (p==0) ? 32 : (p==1) ? 21 : 10;
    unsigned int bmask = (p==2) ? 1023u : 2047u;
    bins[tid] = 0; bins[tid+1024] = 0;
    __syncthreads();
    for (unsigned int i = tid; i < n; i += 1024){
      unsigned int k32 = (unsigned int)(cd[i] >> 32);
      bool m = (mshift >= 32) || ((k32 >> mshift) == (prefix >> mshift));
      if (m) atomicAdd(&bins[(k32 >> shift) & bmask], 1u);
    }
    __syncthreads();
    // parallel suffix-sum over 2048 bins (Hillis-Steele)
    for (int off = 1; off < 2048; off <<= 1){
      unsigned int a0 = bins[tid]      + ((tid+off      < 2048) ? bins[tid+off]      : 0u);
      unsigned int a1 = bins[tid+1024] + ((tid+1024+off < 2048) ? bins[tid+1024+off] : 0u);
      __syncthreads();
      bins[tid] = a0; bins[tid+1024] = a1;
      __syncthreads();
    }
    // unique d with S[d] >= rem > S[d+1]
    #pragma unroll
    for (int h = 0; h < 2; ++h){
      int d = tid + h*1024;
      unsigned int Sd  = bins[d];
      unsigned int Sd1 = (d < 2047) ? bins[d+1] : 0u;
      if (Sd >= rem && Sd1 < rem){ scal[0] = rem - Sd1; scal[1] = (unsigned int)d; }
    }
    __syncthreads();
    rem = scal[0]; prefix |= scal[1] << shift;
    __syncthreads();
  }
  unsigned int T = prefix;
  unsigned int G = PRE_K - rem;   // # strictly greater than T; rem ties needed
  if (tid == 0){ scal[2] = 0; scal[3] = 0; }
  __syncthreads();
  for (unsigned int i = tid; i < n; i += 1024){
    unsigned long long pk = cd[i];
    unsigned int k32 = (unsigned int)(pk >> 32);
    if (k32 > T){
      unsigned int s = atomicAdd(&scal[2], 1u);   // s < G <= 1999
      sel_l[s] = pk;
    } else if (k32 == T){
      unsigned int e = atomicAdd(&scal[3], 1u);
      if (G + e < SORT_N) sel_l[G + e] = pk;      // ties; first rem after sort = smallest idx
    }
  }
  __syncthreads();
  unsigned int ceq = scal[3];
  unsigned int tcap = SORT_N - G;
  unsigned int filled = G + ((ceq < tcap) ? ceq : tcap);
  for (unsigned int i = filled + tid; i < SORT_N; i += 1024) sel_l[i] = 0ull;
  __syncthreads();
  // bitonic sort 2048 descending: (key desc, idx asc) via ~idx packing
  for (int k = 2; k <= SORT_N; k <<= 1){
    for (int j = k >> 1; j > 0; j >>= 1){
      for (int i = tid; i < SORT_N; i += 1024){
        int ixj = i ^ j;
        if (ixj > i){
          bool up = ((i & k) == 0);
          unsigned long long x = sel_l[i], y = sel_l[ixj];
          if ((x < y) == up){ sel_l[i] = y; sel_l[ixj] = x; }
        }
      }
      __syncthreads();
    }
  }
  // decode + clip the exact top-2000 (score rebuilt bit-exactly from key)
  for (int k = tid; k < PRE_K; k += 1024){
    unsigned long long pk = sel_l[k];
    unsigned int key = (unsigned int)(pk >> 32);
    unsigned int idx = ~(unsigned int)(pk & 0xFFFFFFFFull);
    unsigned int ub = (key & 0x80000000u) ? (key ^ 0x80000000u) : (key ^ 0xFFFFFFFFu);
    float sc = __uint_as_float(ub);
    float4 a = ((const float4*)anchors)[idx];
    float4 d = ((const float4*)deltas)[(size_t)img*N_ANCH + idx];
    float w  = rn_add(rn_sub(a.z, a.x), 1.0f);
    float h  = rn_add(rn_sub(a.w, a.y), 1.0f);
    float cx = rn_add(a.x, rn_mul(0.5f, w));
    float cy = rn_add(a.y, rn_mul(0.5f, h));
    float dw = fminf(d.z, DCLIP);
    float dh = fminf(d.w, DCLIP);
    float pcx = rn_add(rn_mul(d.x, w), cx);
    float pcy = rn_add(rn_mul(d.y, h), cy);
    float pw = rn_mul((float)exp((double)dw), w);   // correctly-rounded f32 exp
    float ph = rn_mul((float)exp((double)dh), h);
    float x1 = rn_sub(pcx, rn_mul(0.5f, pw));
    float y1 = rn_sub(pcy, rn_mul(0.5f, ph));
    float x2 = rn_sub(rn_add(pcx, rn_mul(0.5f, pw)), 1.0f);
    float y2 = rn_sub(rn_add(pcy, rn_mul(0.5f, ph)), 1.0f);
    x1 = fminf(fmaxf(x1, 0.0f), IMG_W_M1);
    x2 = fminf(fmaxf(x2, 0.0f), IMG_W_M1);
    y1 = fminf(fmaxf(y1, 0.0f), IMG_H_M1);
    y2 = fminf(fmaxf(y2, 0.0f), IMG_H_M1);
    float bw = rn_add(rn_sub(x2, x1), 1.0f);
    float bh = rn_add(rn_sub(y2, y1), 1.0f);
    ((float4*)boxes)[(size_t)img*PRE_K + k] = make_float4(x1, y1, x2, y2);
    scores[img*PRE_K + k] = sc;
    areas[img*PRE_K + k]  = rn_mul(bw, bh);
    valid[img*PRE_K + k]  = (bw >= 0.0f && bh >= 0.0f) ? 1u : 0u;
  }
}

// ---------------- NMS suppression bitmask (upper triangle) ----------------
__global__ void k_mask(const float* __restrict__ boxes, const float* __restrict__ areas,
                       unsigned long long* __restrict__ mask){
  int jblk = blockIdx.x, iblk = blockIdx.y, img = blockIdx.z;
  if (jblk < iblk) return;
  __shared__ float4 jb[64];
  __shared__ float  ja[64];
  int tj = jblk*64 + threadIdx.x;
  if (tj < PRE_K){
    jb[threadIdx.x] = ((const float4*)boxes)[(size_t)img*PRE_K + tj];
    ja[threadIdx.x] = areas[img*PRE_K + tj];
  }
  __syncthreads();
  int i = iblk*64 + threadIdx.x;
  if (i >= PRE_K) return;
  float4 bi = ((const float4*)boxes)[(size_t)img*PRE_K + i];
  float ai = areas[img*PRE_K + i];
  unsigned long long bits = 0;
  int jmax = min(64, PRE_K - jblk*64);
  for (int b = 0; b < jmax; ++b){
    int j = jblk*64 + b;
    if (j <= i) continue;
    float4 bj = jb[b];
    if (iou_gt(bi.x,bi.y,bi.z,bi.w,ai, bj.x,bj.y,bj.z,bj.w,ja[b])) bits |= 1ull << b;
  }
  mask[((size_t)img*PRE_K + i)*NMS_WORDS + jblk] = bits;
}

// ---------------- pipelined greedy reduce + output pack (proven r4 version) ----------------
__global__ void __launch_bounds__(1024) k_nms_out(const unsigned long long* __restrict__ mask,
                          const unsigned int* __restrict__ valid,
                          const float* __restrict__ boxes, const float* __restrict__ scores,
                          float* __restrict__ out){
  __shared__ unsigned long long lbuf[2][64 * NMS_WORDS];  // 2 x 16 KB
  __shared__ unsigned long long keepw[NMS_WORDS];
  __shared__ unsigned int kpre[NMS_WORDS + 1];
  int img = blockIdx.x;
  int tid = threadIdx.x;
  const unsigned long long* mrow = mask + (size_t)img * PRE_K * NMS_WORDS;
  const int TOT_U64 = PRE_K * NMS_WORDS;  // 64000

  unsigned long long remv = 0;
  if (tid < NMS_WORDS){
    for (int b = 0; b < 64; ++b){
      int i = tid*64 + b;
      bool ok = (i < PRE_K) && (valid[img*PRE_K + i] != 0u);
      if (!ok) remv |= 1ull << b;
    }
  }

  int lt = tid - 64;  // loader threads 64..575
  if (lt >= 0 && lt < 512){
    int e0 = lt * 4;
    ulonglong2 v0, v1; v0.x = v0.y = v1.x = v1.y = 0ull;
    if (e0 < TOT_U64){
      const ulonglong2* g = (const ulonglong2*)(mrow + e0);
      v0 = g[0]; v1 = g[1];
    }
    ulonglong2* l = (ulonglong2*)&lbuf[0][e0];
    l[0] = v0; l[1] = v1;
  }
  __syncthreads();

  for (int c = 0; c < NCHUNK; ++c){
    if (lt >= 0 && lt < 512 && (c + 1) < NCHUNK){
      int e0 = lt * 4;
      int off = (c + 1) * (64 * NMS_WORDS) + e0;
      ulonglong2 v0, v1; v0.x = v0.y = v1.x = v1.y = 0ull;
      if (off < TOT_U64){
        const ulonglong2* g = (const ulonglong2*)(mrow + off);
        v0 = g[0]; v1 = g[1];
      }
      ulonglong2* l = (ulonglong2*)&lbuf[(c + 1) & 1][e0];
      l[0] = v0; l[1] = v1;
    }
    if (tid < 64){
      const unsigned long long* B = &lbuf[c & 1][0];
      int w = tid;
      int wm = w & (NMS_WORDS - 1);
      unsigned long long k = ~shfl_u64(remv, c);
      unsigned long long acc = 0;
      for (int s = 0; s < 64; s += 8){
        const unsigned long long* Br = B + (size_t)s * NMS_WORDS;
        unsigned long long dg0 = Br[0*NMS_WORDS + c], rw0 = Br[0*NMS_WORDS + wm];
        unsigned long long dg1 = Br[1*NMS_WORDS + c], rw1 = Br[1*NMS_WORDS + wm];
        unsigned long long dg2 = Br[2*NMS_WORDS + c], rw2 = Br[2*NMS_WORDS + wm];
        unsigned long long dg3 = Br[3*NMS_WORDS + c], rw3 = Br[3*NMS_WORDS + wm];
        unsigned long long dg4 = Br[4*NMS_WORDS + c], rw4 = Br[4*NMS_WORDS + wm];
        unsigned long long dg5 = Br[5*NMS_WORDS + c], rw5 = Br[5*NMS_WORDS + wm];
        unsigned long long dg6 = Br[6*NMS_WORDS + c], rw6 = Br[6*NMS_WORDS + wm];
        unsigned long long dg7 = Br[7*NMS_WORDS + c], rw7 = Br[7*NMS_WORDS + wm];
        unsigned long long m;
        m = ((k >> (s+0)) & 1ull) ? ~0ull : 0ull; k &= ~(dg0 & m); acc |= rw0 & m;
        m = ((k >> (s+1)) & 1ull) ? ~0ull : 0ull; k &= ~(dg1 & m); acc |= rw1 & m;
        m = ((k >> (s+2)) & 1ull) ? ~0ull : 0ull; k &= ~(dg2 & m); acc |= rw2 & m;
        m = ((k >> (s+3)) & 1ull) ? ~0ull : 0ull; k &= ~(dg3 & m); acc |= rw3 & m;
        m = ((k >> (s+4)) & 1ull) ? ~0ull : 0ull; k &= ~(dg4 & m); acc |= rw4 & m;
        m = ((k >> (s+5)) & 1ull) ? ~0ull : 0ull; k &= ~(dg5 & m); acc |= rw5 & m;
        m = ((k >> (s+6)) & 1ull) ? ~0ull : 0ull; k &= ~(dg6 & m); acc |= rw6 & m;
        m = ((k >> (s+7)) & 1ull) ? ~0ull : 0ull; k &= ~(dg7 & m); acc |= rw7 & m;
      }
      if (w == c)                      remv = ~k;
      else if (w > c && w < NMS_WORDS) remv |= acc;
    }
    __syncthreads();
  }

  if (tid < NMS_WORDS) keepw[tid] = ~remv;
  __syncthreads();
  if (tid == 0){
    unsigned int s = 0;
    for (int w = 0; w < NMS_WORDS; ++w){ kpre[w] = s; s += __popcll(keepw[w]); }
    kpre[NMS_WORDS] = s;
  }
  __syncthreads();
  unsigned int nkept = kpre[NMS_WORDS];
  for (int i = tid; i < PRE_K; i += blockDim.x){
    int w = i >> 6, b = i & 63;
    unsigned long long kw = keepw[w];
    bool kept = (kw >> b) & 1ull;
    unsigned long long below = (b == 0) ? 0ull : (kw & ((~0ull) >> (64 - b)));
    unsigned int rank = kpre[w] + (unsigned int)__popcll(below);
    unsigned int pos = kept ? rank : (nkept + (unsigned int)i - rank);
    if (pos < POST_K){
      float4 bx = ((const float4*)boxes)[(size_t)img*PRE_K + i];
      float sc = kept ? scores[img*PRE_K + i] : -1e9f;
      float* o = out + ((size_t)img*POST_K + pos) * 5;
      o[0] = bx.x; o[1] = bx.y; o[2] = bx.z; o[3] = bx.w; o[4] = sc;
    }
  }
}

extern "C" void kernel_launch(void* const* d_in, const int* in_sizes, int n_in,
                              void* d_out, int out_size, void* d_ws, size_t ws_size,
                              hipStream_t stream) {
  const float* anchors    = (const float*)d_in[0];
  const float* objectness = (const float*)d_in[1];
  const float* deltas     = (const float*)d_in[2];
  float* out = (float*)d_out;
  char* ws = (char*)d_ws;

  unsigned int* hist       = (unsigned int*)(ws + 0);        // 65536
  unsigned int* state      = (unsigned int*)(ws + 65536);    // 32
  unsigned int* cnt        = (unsigned int*)(ws + 65600);    // 2048 (256B/img)
  float* boxes             = (float*)(ws + 67648);           // 256000 (16B aligned)
  float* scores            = (float*)(ws + 323648);          // 64000
  float* areas             = (float*)(ws + 387648);          // 64000
  unsigned int* valid      = (unsigned int*)(ws + 451648);   // 64000
  unsigned long long* mask = (unsigned long long*)(ws + 515648); // 4096000
  // candidate buffer overlays mask region: fully consumed by k_selsort BEFORE
  // k_mask writes mask (in-order stream). 8*8192*8 = 512 KB <= 4 MB.
  unsigned long long* cand = (unsigned long long*)(ws + 515648);

  hipLaunchKernelGGL(k_init, dim3(32), dim3(256), 0, stream, hist, cnt);
  hipLaunchKernelGGL(k_hist, dim3(8, N_IMG), dim3(256), 0, stream, objectness, hist);
  hipLaunchKernelGGL(k_scan, dim3(N_IMG), dim3(64), 0, stream, hist, state);
  hipLaunchKernelGGL(k_cand, dim3(32, N_IMG), dim3(256), 0, stream,
                     objectness, state, cnt, cand);
  hipLaunchKernelGGL(k_selsort, dim3(N_IMG), dim3(1024), 0, stream,
                     cand, cnt, anchors, deltas, boxes, scores, areas, valid);
  hipLaunchKernelGGL(k_mask, dim3(NMS_WORDS, NMS_WORDS, N_IMG), dim3(64), 0, stream,
                     boxes, areas, mask);
  hipLaunchKernelGGL(k_nms_out, dim3(N_IMG), dim3(1024), 0, stream,
                     mask, valid, boxes, scores, out);
}